// Round 10
// baseline (108.974 us; speedup 1.0000x reference)
//
#include <hip/hip_runtime.h>
#include <hip/hip_bf16.h>

#define EPSF 1e-7f
#define B_ 8
#define H_ 64
#define W_ 64
#define C_ 32
#define HO 58
#define WO 58
#define NF 64
#define KDIM 800

#define XBS 40      // xtb col stride (bf16): 80B -> +20 banks/col, 16B-aligned
#define RS  808     // rot row stride (bf16): >= 25*32=800 needed! 1616B -> +20 banks/row, conflict-free (R7-proven)

typedef __bf16 v8bf __attribute__((ext_vector_type(8)));
typedef float  v4f  __attribute__((ext_vector_type(4)));
typedef float  v2f  __attribute__((ext_vector_type(2)));

// ---- pack W into MFMA B-fragment order, bf16 ----
// Wp[((nt*25+kb)*64+lane)*8+j] = W[f=nt*16+(lane&15)][k=kb*32+(lane>>4)*8+j]
__global__ void k_wpack(const float* __restrict__ W, __bf16* __restrict__ Wp) {
    int t = blockIdx.x*256 + threadIdx.x;   // 51200 total
    int j = t & 7; int lane = (t >> 3) & 63; int rest = t >> 9;
    int kb = rest % 25; int nt = rest / 25;
    int f = nt*16 + (lane & 15);
    int k = kb*32 + (lane >> 4)*8 + j;
    Wp[t] = (__bf16)W[f*KDIM + k];
}

// ---- fused, 2 vertical tiles/block: stage8 -> angle32 -> [rot->MFMA]x2 ----
__global__ __launch_bounds__(256, 3)
void k_main(const float* __restrict__ x, const v8bf* __restrict__ Wp,
            const float* __restrict__ bias, float* __restrict__ out) {
    __shared__ __bf16 xtb[8][22][XBS];    // 14,080 B
    __shared__ __bf16 rot[16][RS];        // 25,856 B
    __shared__ float  Srow[8][22];        //    704 B  -> 40,640 B (4/CU by LDS)

    int tid = threadIdx.x;
    int wv = tid >> 6, lane = tid & 63;
    int m = lane & 15, q = lane >> 4;

    // XCD-aware remap over 928 blocks: one batch b per XCD.
    int L = blockIdx.x + 4*(blockIdx.y + 29*blockIdx.z);
    int newL = (L & 7)*116 + (L >> 3);
    int b   = newL / 116;
    int rem = newL - b*116;
    int hog = rem >> 2;
    int wt  = rem & 3;
    int ho0 = hog*2;                              // tiles at rows ho0, ho0+1

    int wo0 = wt*16;
    int npx = WO - wo0; if (npx > 16) npx = 16;   // 16,16,16,10
    int ncols = npx + 6;                          // 22 or 16

    float bv = bias[wv*16 + m];

    // phase 0: stage 8 rows x ncols cols x 32ch; fp32 sums -> Srow, bf16 -> xtb
    if (tid < 8*ncols) {
        int r, c;
        if (ncols == 22) { r = tid/22; c = tid - r*22; }
        else             { r = tid >> 4; c = tid & 15; }
        const float* src = x + (size_t)((b*H_ + ho0 + r)*W_ + wo0 + c)*C_;
        float4 vq[8];
#pragma unroll
        for (int qq = 0; qq < 8; qq++) vq[qq] = *(const float4*)(src + qq*4);
        float s = 0.f;
#pragma unroll
        for (int qq = 0; qq < 8; qq++) s += vq[qq].x + vq[qq].y + vq[qq].z + vq[qq].w;
        Srow[r][c] = s;
#pragma unroll
        for (int h8 = 0; h8 < 4; h8++) {
            v8bf o;
            o[0]=(__bf16)vq[h8*2].x;   o[1]=(__bf16)vq[h8*2].y;
            o[2]=(__bf16)vq[h8*2].z;   o[3]=(__bf16)vq[h8*2].w;
            o[4]=(__bf16)vq[h8*2+1].x; o[5]=(__bf16)vq[h8*2+1].y;
            o[6]=(__bf16)vq[h8*2+1].z; o[7]=(__bf16)vq[h8*2+1].w;
            *(v8bf*)&xtb[r][c][h8*8] = o;
        }
    }
    __syncthreads();

    // phase 2: 8 lanes per pixel, 32 px total. Lane l: group g=l>>3 (pixel
    // t=g&1, col=4wv+(g>>1)), slot s=l&7 handles window row i=s (7 terms).
    int slot = lane & 7;
    int g = (lane >> 3) & 7;
    int myT = g & 1;
    int myC = wv*4 + (g >> 1);                    // == 4wv+q for this lane
    float den = 0.f, crn = 0.f, ccn = 0.f;
    if (slot < 7) {
#pragma unroll
        for (int j = 0; j < 7; j++) {
            float v = Srow[myT + slot][myC + j];
            den += v; crn += v*(float)slot; ccn += v*(float)j;
        }
    }
#pragma unroll
    for (int msk = 1; msk <= 4; msk <<= 1) {
        den += __shfl_xor(den, msk);
        crn += __shfl_xor(crn, msk);
        ccn += __shfl_xor(ccn, msk);
    }
    float pc, ps, pxo, pyo;   // params of pixel (myT, myC)
    {
        float dt = den + EPSF;
        float cr = crn/dt - 3.0f;
        float cx = ccn/dt - 3.0f + EPSF;
        float r2 = cr*cr + cx*cx;
        float inv = r2 > 0.f ? rsqrtf(r2) : 0.f;
        float c = r2 > 0.f ? cx*inv : 1.0f;
        float s = cr*inv;
        const float scale = 1.0f + EPSF;
        pc  = c/scale; ps = s/scale;
        pxo = (6.0f - (c*6.0f - s*6.0f))*0.5f/scale;
        pyo = (6.0f - (s*6.0f + c*6.0f))*0.5f/scale;
    }
    // other tile's params for the same column live in lane^8
    float pc2  = __shfl_xor(pc, 8),  ps2  = __shfl_xor(ps, 8);
    float pxo2 = __shfl_xor(pxo, 8), pyo2 = __shfl_xor(pyo, 8);

    // bilinear writer: pixel col pxl of tile t -> rot[pxl][pos*32..]
    auto do_rot = [&](int t, int pos, float c_, float s_, float xo_, float yo_) {
        int pxl = wv*4 + q;
        int py = pos/5; int yy = py + 1; int xx = pos - py*5 + 1;
        float xin = c_*(float)xx - s_*(float)yy + xo_;
        float yin = s_*(float)xx + c_*(float)yy + yo_;
        float x0f = floorf(xin), y0f = floorf(yin);
        float wx1 = xin - x0f, wx0 = 1.0f - wx1;
        float wy1 = yin - y0f, wy0 = 1.0f - wy1;
        int ix0 = (int)x0f, iy0 = (int)y0f;
        int ix1 = ix0 + 1,  iy1 = iy0 + 1;

        const __bf16* bp[4]; float wgt[4];
        auto mkcorner = [&](int yi, int xi, float w, int idx) {
            bool valid = (xi >= 0) & (xi < 7) & (yi >= 0) & (yi < 7);
            int cy = yi < 0 ? 0 : (yi > 6 ? 6 : yi);
            int cx2 = xi < 0 ? 0 : (xi > 6 ? 6 : xi);
            bp[idx]  = &xtb[t + cy][pxl + cx2][0];
            wgt[idx] = valid ? w : 0.0f;
        };
        mkcorner(iy0, ix0, wy0*wx0, 0);
        mkcorner(iy0, ix1, wy0*wx1, 1);
        mkcorner(iy1, ix0, wy1*wx0, 2);
        mkcorner(iy1, ix1, wy1*wx1, 3);

        v2f acc[16];
#pragma unroll
        for (int i = 0; i < 16; i++) acc[i] = (v2f){0.f, 0.f};
#pragma unroll
        for (int cn = 0; cn < 4; cn++) {
            const __bf16* src = bp[cn];
            v2f wq2 = (v2f){wgt[cn], wgt[cn]};
#pragma unroll
            for (int q8 = 0; q8 < 4; q8++) {
                union { v8bf v; unsigned u[4]; } uv;
                uv.v = *(const v8bf*)(src + q8*8);
#pragma unroll
                for (int d = 0; d < 4; d++) {
                    v2f val = (v2f){ __uint_as_float(uv.u[d] << 16),
                                     __uint_as_float(uv.u[d] & 0xffff0000u) };
                    acc[q8*4 + d] += wq2 * val;   // v_pk_fma_f32
                }
            }
        }
#pragma unroll
        for (int q8 = 0; q8 < 4; q8++) {
            v8bf o;
#pragma unroll
            for (int d = 0; d < 4; d++) {
                o[2*d]   = (__bf16)acc[q8*4 + d].x;
                o[2*d+1] = (__bf16)acc[q8*4 + d].y;
            }
            *(v8bf*)&rot[pxl][pos*32 + q8*8] = o;
        }
    };

    // tile-0 params for this lane's column (select own vs partner copy)
    float c0 = (myT == 0) ? pc : pc2,   s0 = (myT == 0) ? ps : ps2;
    float xo0 = (myT == 0) ? pxo : pxo2, yo0 = (myT == 0) ? pyo : pyo2;
    float c1 = (myT == 1) ? pc : pc2,   s1 = (myT == 1) ? ps : ps2;
    float xo1 = (myT == 1) ? pxo : pxo2, yo1 = (myT == 1) ? pyo : pyo2;

    // all 25 B-fragments, loaded once, reused for both tiles (100 VGPRs)
    const v8bf* wp = Wp + (size_t)wv*25*64 + lane;
    v8bf bfrag[25];
#pragma unroll
    for (int kb = 0; kb < 25; kb++) bfrag[kb] = wp[kb*64];

    v4f accT0 = {0.f, 0.f, 0.f, 0.f};
    v4f accT1 = {0.f, 0.f, 0.f, 0.f};

    // ---- tile 0 ----
#pragma unroll
    for (int rnd = 0; rnd < 2; rnd++) {
        int pos = m + 16*rnd;
        if (pos < 25) do_rot(0, pos, c0, s0, xo0, yo0);
    }
    __syncthreads();
#pragma unroll
    for (int kb = 0; kb < 25; kb++) {
        v8bf a = *(const v8bf*)&rot[m][kb*32 + q*8];
        accT0 = __builtin_amdgcn_mfma_f32_16x16x32_bf16(a, bfrag[kb], accT0, 0, 0, 0);
    }
    __syncthreads();   // rot reads done before tile-1 overwrite

    // ---- tile 1 ----
#pragma unroll
    for (int rnd = 0; rnd < 2; rnd++) {
        int pos = m + 16*rnd;
        if (pos < 25) do_rot(1, pos, c1, s1, xo1, yo1);
    }
    __syncthreads();
#pragma unroll
    for (int kb = 0; kb < 25; kb++) {
        v8bf a = *(const v8bf*)&rot[m][kb*32 + q*8];
        accT1 = __builtin_amdgcn_mfma_f32_16x16x32_bf16(a, bfrag[kb], accT1, 0, 0, 0);
    }

    int f = wv*16 + m;          // C/D col = lane&15 -> filter
    int pixbase0 = (b*HO + ho0)*WO + wo0;
    int pixbase1 = pixbase0 + WO;
#pragma unroll
    for (int r = 0; r < 4; r++) {
        int px = q*4 + r;       // C/D row = (lane>>4)*4 + reg -> pixel col
        if (px < npx) {
            out[(size_t)(pixbase0 + px)*NF + f] = accT0[r] + bv;
            out[(size_t)(pixbase1 + px)*NF + f] = accT1[r] + bv;
        }
    }
}

extern "C" void kernel_launch(void* const* d_in, const int* in_sizes, int n_in,
                              void* d_out, int out_size, void* d_ws, size_t ws_size,
                              hipStream_t stream) {
    const float* x    = (const float*)d_in[0];
    const float* W    = (const float*)d_in[1];
    const float* bias = (const float*)d_in[2];
    float* out = (float*)d_out;
    __bf16* Wp = (__bf16*)d_ws;                    // 102,400 B

    k_wpack<<<dim3(200), 256, 0, stream>>>(W, Wp);
    k_main<<<dim3(4, 29, B_), 256, 0, stream>>>(x, (const v8bf*)Wp, bias, out);
}

// Round 11
// 75.676 us; speedup vs baseline: 1.4400x; 1.4400x over previous
//
#include <hip/hip_runtime.h>
#include <hip/hip_bf16.h>

#define EPSF 1e-7f
#define B_ 8
#define H_ 64
#define W_ 64
#define C_ 32
#define HO 58
#define WO 58
#define NF 64
#define KDIM 800

#define XBS 40      // xtb col stride (bf16): 80B -> +20 banks/col, 16B-aligned
#define RS  808     // rot row stride (bf16): >=800; 1616B -> +20 banks/row (R7-proven)

typedef __bf16 v8bf __attribute__((ext_vector_type(8)));
typedef float  v4f  __attribute__((ext_vector_type(4)));
typedef float  v2f  __attribute__((ext_vector_type(2)));

// ---- pack W into MFMA B-fragment order, bf16 ----
// Wp[((nt*25+kb)*64+lane)*8+j] = W[f=nt*16+(lane&15)][k=kb*32+(lane>>4)*8+j]
__global__ void k_wpack(const float* __restrict__ W, __bf16* __restrict__ Wp) {
    int t = blockIdx.x*256 + threadIdx.x;   // 51200 total
    int j = t & 7; int lane = (t >> 3) & 63; int rest = t >> 9;
    int kb = rest % 25; int nt = rest / 25;
    int f = nt*16 + (lane & 15);
    int k = kb*32 + (lane >> 4)*8 + j;
    Wp[t] = (__bf16)W[f*KDIM + k];
}

// ---- fused, 2 vertical tiles/block; per-tile split bfrag loads (no spill) ----
__global__ __launch_bounds__(256, 4)
void k_main(const float* __restrict__ x, const v8bf* __restrict__ Wp,
            const float* __restrict__ bias, float* __restrict__ out) {
    __shared__ __bf16 xtb[8][22][XBS];    // 14,080 B
    __shared__ __bf16 rot[16][RS];        // 25,856 B
    __shared__ float  Srow[8][22];        //    704 B  -> 40,640 B (4/CU by LDS)

    int tid = threadIdx.x;
    int wv = tid >> 6, lane = tid & 63;
    int m = lane & 15, q = lane >> 4;

    // XCD-aware remap over 928 blocks: one batch b per XCD.
    int L = blockIdx.x + 4*(blockIdx.y + 29*blockIdx.z);
    int newL = (L & 7)*116 + (L >> 3);
    int b   = newL / 116;
    int rem = newL - b*116;
    int hog = rem >> 2;
    int wt  = rem & 3;
    int ho0 = hog*2;                              // tiles at rows ho0, ho0+1

    int wo0 = wt*16;
    int npx = WO - wo0; if (npx > 16) npx = 16;   // 16,16,16,10
    int ncols = npx + 6;                          // 22 or 16

    float bv = bias[wv*16 + m];

    // phase 0: stage 8 rows x ncols cols x 32ch; fp32 sums -> Srow, bf16 -> xtb
    if (tid < 8*ncols) {
        int r, c;
        if (ncols == 22) { r = tid/22; c = tid - r*22; }
        else             { r = tid >> 4; c = tid & 15; }
        const float* src = x + (size_t)((b*H_ + ho0 + r)*W_ + wo0 + c)*C_;
        float4 vq[8];
#pragma unroll
        for (int qq = 0; qq < 8; qq++) vq[qq] = *(const float4*)(src + qq*4);
        float s = 0.f;
#pragma unroll
        for (int qq = 0; qq < 8; qq++) s += vq[qq].x + vq[qq].y + vq[qq].z + vq[qq].w;
        Srow[r][c] = s;
#pragma unroll
        for (int h8 = 0; h8 < 4; h8++) {
            v8bf o;
            o[0]=(__bf16)vq[h8*2].x;   o[1]=(__bf16)vq[h8*2].y;
            o[2]=(__bf16)vq[h8*2].z;   o[3]=(__bf16)vq[h8*2].w;
            o[4]=(__bf16)vq[h8*2+1].x; o[5]=(__bf16)vq[h8*2+1].y;
            o[6]=(__bf16)vq[h8*2+1].z; o[7]=(__bf16)vq[h8*2+1].w;
            *(v8bf*)&xtb[r][c][h8*8] = o;
        }
    }
    __syncthreads();

    // phase 2: 8 lanes per pixel, 32 px total. Lane l: group g=l>>3 (pixel
    // t=g&1, col=4wv+(g>>1)), slot s=l&7 handles window row i=s (7 terms).
    int slot = lane & 7;
    int g = (lane >> 3) & 7;
    int myT = g & 1;
    int myC = wv*4 + (g >> 1);                    // == 4wv+q for this lane
    float den = 0.f, crn = 0.f, ccn = 0.f;
    if (slot < 7) {
#pragma unroll
        for (int j = 0; j < 7; j++) {
            float v = Srow[myT + slot][myC + j];
            den += v; crn += v*(float)slot; ccn += v*(float)j;
        }
    }
#pragma unroll
    for (int msk = 1; msk <= 4; msk <<= 1) {
        den += __shfl_xor(den, msk);
        crn += __shfl_xor(crn, msk);
        ccn += __shfl_xor(ccn, msk);
    }
    float pc, ps, pxo, pyo;   // params of pixel (myT, myC)
    {
        float dt = den + EPSF;
        float cr = crn/dt - 3.0f;
        float cx = ccn/dt - 3.0f + EPSF;
        float r2 = cr*cr + cx*cx;
        float inv = r2 > 0.f ? rsqrtf(r2) : 0.f;
        float c = r2 > 0.f ? cx*inv : 1.0f;
        float s = cr*inv;
        const float scale = 1.0f + EPSF;
        pc  = c/scale; ps = s/scale;
        pxo = (6.0f - (c*6.0f - s*6.0f))*0.5f/scale;
        pyo = (6.0f - (s*6.0f + c*6.0f))*0.5f/scale;
    }
    // other tile's params for the same column live in lane^8
    float pc2  = __shfl_xor(pc, 8),  ps2  = __shfl_xor(ps, 8);
    float pxo2 = __shfl_xor(pxo, 8), pyo2 = __shfl_xor(pyo, 8);

    // bilinear writer: pixel col pxl of tile t -> rot[pxl][pos*32..]
    auto do_rot = [&](int t, int pos, float c_, float s_, float xo_, float yo_) {
        int pxl = wv*4 + q;
        int py = pos/5; int yy = py + 1; int xx = pos - py*5 + 1;
        float xin = c_*(float)xx - s_*(float)yy + xo_;
        float yin = s_*(float)xx + c_*(float)yy + yo_;
        float x0f = floorf(xin), y0f = floorf(yin);
        float wx1 = xin - x0f, wx0 = 1.0f - wx1;
        float wy1 = yin - y0f, wy0 = 1.0f - wy1;
        int ix0 = (int)x0f, iy0 = (int)y0f;
        int ix1 = ix0 + 1,  iy1 = iy0 + 1;

        const __bf16* bp[4]; float wgt[4];
        auto mkcorner = [&](int yi, int xi, float w, int idx) {
            bool valid = (xi >= 0) & (xi < 7) & (yi >= 0) & (yi < 7);
            int cy = yi < 0 ? 0 : (yi > 6 ? 6 : yi);
            int cx2 = xi < 0 ? 0 : (xi > 6 ? 6 : xi);
            bp[idx]  = &xtb[t + cy][pxl + cx2][0];
            wgt[idx] = valid ? w : 0.0f;
        };
        mkcorner(iy0, ix0, wy0*wx0, 0);
        mkcorner(iy0, ix1, wy0*wx1, 1);
        mkcorner(iy1, ix0, wy1*wx0, 2);
        mkcorner(iy1, ix1, wy1*wx1, 3);

        v2f acc[16];
#pragma unroll
        for (int i = 0; i < 16; i++) acc[i] = (v2f){0.f, 0.f};
#pragma unroll
        for (int cn = 0; cn < 4; cn++) {
            const __bf16* src = bp[cn];
            v2f wq2 = (v2f){wgt[cn], wgt[cn]};
#pragma unroll
            for (int q8 = 0; q8 < 4; q8++) {
                union { v8bf v; unsigned u[4]; } uv;
                uv.v = *(const v8bf*)(src + q8*8);
#pragma unroll
                for (int d = 0; d < 4; d++) {
                    v2f val = (v2f){ __uint_as_float(uv.u[d] << 16),
                                     __uint_as_float(uv.u[d] & 0xffff0000u) };
                    acc[q8*4 + d] += wq2 * val;   // v_pk_fma_f32
                }
            }
        }
#pragma unroll
        for (int q8 = 0; q8 < 4; q8++) {
            v8bf o;
#pragma unroll
            for (int d = 0; d < 4; d++) {
                o[2*d]   = (__bf16)acc[q8*4 + d].x;
                o[2*d+1] = (__bf16)acc[q8*4 + d].y;
            }
            *(v8bf*)&rot[pxl][pos*32 + q8*8] = o;
        }
    };

    // tile params for this lane's column (select own vs partner copy)
    float c0 = (myT == 0) ? pc : pc2,   s0 = (myT == 0) ? ps : ps2;
    float xo0 = (myT == 0) ? pxo : pxo2, yo0 = (myT == 0) ? pyo : pyo2;
    float c1 = (myT == 1) ? pc : pc2,   s1 = (myT == 1) ? ps : ps2;
    float xo1 = (myT == 1) ? pxo : pxo2, yo1 = (myT == 1) ? pyo : pyo2;

    const v8bf* wp = Wp + (size_t)wv*25*64 + lane;
    int f = wv*16 + m;
    int pixbase0 = (b*HO + ho0)*WO + wo0;

    // ---- per-tile: rot -> [bfA(13) under barrier] -> MFMA(13) + bfB(12) -> MFMA(12) ----
#pragma unroll
    for (int t = 0; t < 2; t++) {
        float tc  = t ? c1  : c0,  ts  = t ? s1  : s0;
        float txo = t ? xo1 : xo0, tyo = t ? yo1 : yo0;
        if (t) __syncthreads();               // tile-0 rot reads done before overwrite
#pragma unroll
        for (int rnd = 0; rnd < 2; rnd++) {
            int pos = m + 16*rnd;
            if (pos < 25) do_rot(t, pos, tc, ts, txo, tyo);
        }
        v8bf bfA[13];
#pragma unroll
        for (int kb = 0; kb < 13; kb++) bfA[kb] = wp[kb*64];   // hides under barrier
        __syncthreads();

        v8bf bfB[12];
#pragma unroll
        for (int kb = 0; kb < 12; kb++) bfB[kb] = wp[(13 + kb)*64];

        v4f acc0 = {0.f, 0.f, 0.f, 0.f};
        v4f acc1 = {0.f, 0.f, 0.f, 0.f};
#pragma unroll
        for (int kb = 0; kb < 13; kb++) {
            v8bf a = *(const v8bf*)&rot[m][kb*32 + q*8];
            if (kb & 1) acc1 = __builtin_amdgcn_mfma_f32_16x16x32_bf16(a, bfA[kb], acc1, 0, 0, 0);
            else        acc0 = __builtin_amdgcn_mfma_f32_16x16x32_bf16(a, bfA[kb], acc0, 0, 0, 0);
        }
#pragma unroll
        for (int kb = 0; kb < 12; kb++) {
            v8bf a = *(const v8bf*)&rot[m][(13 + kb)*32 + q*8];
            if (kb & 1) acc1 = __builtin_amdgcn_mfma_f32_16x16x32_bf16(a, bfB[kb], acc1, 0, 0, 0);
            else        acc0 = __builtin_amdgcn_mfma_f32_16x16x32_bf16(a, bfB[kb], acc0, 0, 0, 0);
        }

        int pixbase = pixbase0 + t*WO;
#pragma unroll
        for (int r = 0; r < 4; r++) {
            int px = q*4 + r;       // C/D row = (lane>>4)*4 + reg -> pixel col
            if (px < npx) out[(size_t)(pixbase + px)*NF + f] = acc0[r] + acc1[r] + bv;
        }
    }
}

extern "C" void kernel_launch(void* const* d_in, const int* in_sizes, int n_in,
                              void* d_out, int out_size, void* d_ws, size_t ws_size,
                              hipStream_t stream) {
    const float* x    = (const float*)d_in[0];
    const float* W    = (const float*)d_in[1];
    const float* bias = (const float*)d_in[2];
    float* out = (float*)d_out;
    __bf16* Wp = (__bf16*)d_ws;                    // 102,400 B

    k_wpack<<<dim3(200), 256, 0, stream>>>(W, Wp);
    k_main<<<dim3(4, 29, B_), 256, 0, stream>>>(x, (const v8bf*)Wp, bias, out);
}